// Round 16
// baseline (141.722 us; speedup 1.0000x reference)
//
#include <hip/hip_runtime.h>

namespace {

constexpr int NQ = 12;
constexpr int NL = 3;
constexpr int FEAT = 64;
constexpr float PI_F = 3.14159265358979323846f;

typedef float f2 __attribute__((ext_vector_type(2)));

// ============================ constexpr GF(2) toolkit ============================
constexpr int par12(unsigned x) { int p = 0; for (int i = 0; i < 12; ++i) p ^= (int)((x >> i) & 1u); return p; }
constexpr int lead12(unsigned x) { for (int k = 11; k >= 0; --k) if ((x >> k) & 1u) return k; return -1; }

struct Ech { unsigned v[16] = {}; int n = 0; };
constexpr unsigned ech_reduce(const Ech& E, unsigned x) {
  for (int i = 0; i < E.n; ++i) { int lb = lead12(E.v[i]); if (lb >= 0 && ((x >> lb) & 1u)) x ^= E.v[i]; }
  return x;
}
constexpr bool ech_add(Ech& E, unsigned x) {
  unsigned r = ech_reduce(E, x);
  if (!r) return false;
  int lb = lead12(r);
  int pos = E.n;
  for (int i = 0; i < E.n; ++i) { if (lead12(E.v[i]) < lb) { pos = i; break; } }
  for (int i = E.n; i > pos; --i) E.v[i] = E.v[i - 1];
  E.v[pos] = r; E.n++;
  return true;
}

constexpr unsigned apmat(const unsigned* rows, unsigned v) {
  unsigned o = 0; for (int k = 0; k < 12; ++k) if (par12(rows[k] & v)) o |= 1u << k; return o;
}
constexpr bool inv12(const unsigned* in, unsigned* out) {
  unsigned a[12] = {}, b[12] = {};
  for (int k = 0; k < 12; ++k) { a[k] = in[k]; b[k] = 1u << k; }
  for (int c = 0; c < 12; ++c) {
    int p = -1;
    for (int r = c; r < 12; ++r) if ((a[r] >> c) & 1u) { p = r; break; }
    if (p < 0) return false;
    unsigned t = a[c]; a[c] = a[p]; a[p] = t; t = b[c]; b[c] = b[p]; b[p] = t;
    for (int r = 0; r < 12; ++r) if (r != c && ((a[r] >> c) & 1u)) { a[r] ^= a[c]; b[r] ^= b[c]; }
  }
  for (int k = 0; k < 12; ++k) out[k] = b[k];
  return true;
}
constexpr unsigned dropb(unsigned x, int t) {  // remove bit t, shift higher bits down (11-bit result)
  unsigned lm = (1u << t) - 1u;
  return (x & lm) | ((x >> 1) & (0x7FFu & ~lm));
}

// ============ logical circuit tracking (deferred CNOT ring, verified r1-r15) ============
struct Logical {
  unsigned m[NL][NQ] = {}, rv[NL][NQ] = {}, rf[NQ] = {};
  bool ok = false;
};
constexpr Logical compute_raw() {
  Logical mp{};
  unsigned col[NQ] = {}, row[NQ] = {};
  for (int b = 0; b < NQ; ++b) { col[b] = 1u << b; row[b] = 1u << b; }
  mp.ok = true;
  for (int L = 0; L < NL; ++L) {
    for (int q = 0; q < NQ; ++q) {
      mp.m[L][q]  = col[NQ - 1 - q];
      mp.rv[L][q] = row[NQ - 1 - q];
      if (par12(mp.m[L][q] & mp.rv[L][q]) != 1) mp.ok = false;
    }
    for (int q = 0; q < NQ; ++q) {
      int bc = NQ - 1 - q;
      int bt = NQ - 1 - ((q + 1) % NQ);
      col[bc] ^= col[bt];
      row[bt] ^= row[bc];
    }
  }
  for (int q = 0; q < NQ; ++q) mp.rf[q] = row[NQ - 1 - q];
  return mp;
}

// ============================ phase/remap plan (VERIFIED r10-r15) ============================
struct Plan {
  unsigned l0m[NQ] = {}, l0r[NQ] = {};
  unsigned gm[4][6] = {};
  unsigned gr[4][6] = {};
  unsigned rf[NQ] = {};
  unsigned phi[4][6] = {};
  unsigned coffE[4][64] = {};
  int cb[4] = {};
  bool ok = false;
};

constexpr bool findH(const Ech& G, unsigned rho, unsigned& out) {
  for (unsigned t = 0; t < 12; ++t) {
    unsigned v = 1u << t;
    if (par12(v & rho) == 0 && ech_reduce(G, v)) { out = v; return true; }
  }
  for (unsigned v = 1; v < 4096u; ++v) {
    if (par12(v & rho) == 0 && ech_reduce(G, v)) { out = v; return true; }
  }
  return false;
}

constexpr Plan build_plan() {
  Logical raw = compute_raw();
  Plan P{};
  P.ok = raw.ok;
  for (int q = 0; q < NQ; ++q) { P.l0m[q] = raw.m[0][q]; P.l0r[q] = raw.rv[0][q]; }
  unsigned fwd[12] = {}, invc[12] = {};
  for (int k = 0; k < 12; ++k) { fwd[k] = 1u << k; invc[k] = 1u << k; }
  for (int ph = 0; ph < 4; ++ph) {
    const int L = 1 + ph / 2, q0 = (ph % 2) * 6;
    unsigned ml[6] = {};
    for (int i = 0; i < 6; ++i) ml[i] = raw.m[L][q0 + i];
    bool done = false;
    for (int cbi = 5; cbi >= 0 && !done; --cbi) {
      unsigned rho = fwd[6 + cbi];
      bool bad = false;
      int idx = -1;
      for (int i = 0; i < 6; ++i) if (par12(ml[i] & rho)) { idx = i; break; }
      unsigned uc = 0;
      Ech W{};
      if (idx >= 0) {
        uc = ml[idx];
        for (int i = 0; i < 6; ++i) {
          if (i == idx) continue;
          unsigned w = par12(ml[i] & rho) ? (ml[i] ^ uc) : ml[i];
          ech_add(W, w);
        }
        if (W.n > 5) bad = true;
      } else {
        for (int i = 0; i < 6; ++i) ech_add(W, ml[i]);
        if (W.n > 5) bad = true;
        if (!bad) {
          bool got = false;
          for (unsigned t = 0; t < 12 && !got; ++t) {
            unsigned v = 1u << t;
            if (par12(v & rho)) { uc = v; got = true; }
          }
          if (!got) bad = true;
        }
      }
      if (bad) continue;
      Ech G{};
      for (int i = 0; i < W.n && !bad; ++i) if (!ech_add(G, W.v[i])) bad = true;
      if (!bad && !ech_add(G, uc)) bad = true;
      if (bad) continue;
      unsigned regH[5] = {};
      int nH = W.n;
      for (int i = 0; i < nH; ++i) regH[i] = W.v[i];
      for (int slot = nH; slot < 5 && !bad; ++slot) {
        unsigned v = 0;
        if (!findH(G, rho, v)) { bad = true; break; }
        regH[slot] = v; ech_add(G, v);
      }
      if (bad) continue;
      unsigned lam[6] = {};
      for (int j = 0; j < 6 && !bad; ++j) {
        unsigned cand = invc[j];
        if (par12(cand & rho) != 0 || !ech_reduce(G, cand)) {
          if (!findH(G, rho, cand)) { bad = true; break; }
        }
        lam[j] = cand; ech_add(G, cand);
      }
      if (bad) continue;
      unsigned ncols[12] = {};
      for (int j = 0; j < 6; ++j) ncols[j] = lam[j];
      {
        int w = 0;
        for (int k = 0; k < 6; ++k) ncols[6 + k] = (k == cbi) ? uc : regH[w++];
      }
      unsigned Mrows[12] = {};
      for (int k = 0; k < 12; ++k) {
        unsigned r = 0;
        for (int j = 0; j < 12; ++j) r |= ((ncols[j] >> k) & 1u) << j;
        Mrows[k] = r;
      }
      unsigned fnew[12] = {};
      if (!inv12(Mrows, fnew)) continue;
      bool okp = true;
      unsigned gmv[6] = {}, grv[6] = {};
      for (int i = 0; i < 6 && okp; ++i) {
        unsigned SM = apmat(fnew, ml[i]);
        if (SM & 63u) okp = false;
        unsigned sg = 0;
        for (int k = 0; k < 12; ++k) if (par12(raw.rv[L][q0 + i] & ncols[k])) sg |= 1u << k;
        if (par12(SM & sg) != 1) okp = false;
        gmv[i] = SM; grv[i] = sg;
      }
      unsigned phj[6] = {}, Ust[6] = {};
      for (int j = 0; j < 6 && okp; ++j) {
        phj[j] = apmat(fwd, lam[j]);
        if ((phj[j] >> (6 + cbi)) & 1u) okp = false;
      }
      for (int k = 0; k < 6 && okp; ++k) {
        Ust[k] = apmat(fwd, ncols[6 + k]);
        if (((Ust[k] >> (6 + cbi)) & 1u) != (unsigned)(k == cbi ? 1 : 0)) okp = false;
      }
      if (!okp) continue;
      P.cb[ph] = cbi;
      for (int j = 0; j < 6; ++j) P.phi[ph][j] = phj[j];
      for (int rp = 0; rp < 64; ++rp) {
        unsigned psi = 0;
        for (int i = 0; i < 6; ++i) if ((rp >> i) & 1) psi ^= Ust[i];
        P.coffE[ph][rp] = dropb(psi, 6 + cbi);
      }
      for (int i = 0; i < 6; ++i) { P.gm[ph][i] = gmv[i]; P.gr[ph][i] = grv[i]; }
      for (int k = 0; k < 12; ++k) { fwd[k] = fnew[k]; invc[k] = ncols[k]; }
      done = true;
    }
    if (!done) { P.ok = false; return P; }
  }
  for (int q = 0; q < NQ; ++q) {
    unsigned sg = 0;
    for (int k = 0; k < 12; ++k) if (par12(raw.rf[q] & invc[k])) sg |= 1u << k;
    P.rf[q] = sg;
  }
  return P;
}

constexpr Plan PLAN = build_plan();
static_assert(PLAN.ok, "plan construction failed");

// ============================ math (plain C++, verified r14 = fastest) ============================
// CDNA4 has no packed-FP32 rate doubling (157.3 TF peak == scalar FMA rate), so scalar
// compiler-generated FMAs reading AGPR-resident state directly ARE the arithmetic floor.
__device__ __forceinline__ f2 shuf(f2 a) { return __builtin_shufflevector(a, a, 1, 0); }

template<bool REAL>
__device__ __forceinline__ f2 updv(f2 a, f2 p, f2 arr, f2 aii, f2 brr, f2 bii) {
  f2 t = a * arr;
  if constexpr (!REAL) t = shuf(a) * aii + t;
  t = p * brr + t;
  if constexpr (!REAL) t = shuf(p) * bii + t;
  return t;
}
__device__ __forceinline__ f2 cmulv(f2 a, f2 urr, f2 uri) {
  return shuf(a) * uri + a * urr;
}

template<unsigned MLO>
__device__ __forceinline__ float shx(float v, int lane4) {
  if constexpr (MLO == 0u) {
    return v;
  } else if constexpr (MLO < 32u) {
    constexpr int off = (int)((MLO << 10) | 0x1fu);
    return __int_as_float(__builtin_amdgcn_ds_swizzle(__float_as_int(v), off));
  } else {
    int addr = lane4 ^ (int)(MLO << 2);
    return __int_as_float(__builtin_amdgcn_ds_bpermute(addr, __float_as_int(v)));
  }
}

template<unsigned M, unsigned R, int NREG, bool REAL>
__device__ __forceinline__ void gate(f2* st, float ghalf, float phihalf, int lane, int lane4) {
  float s, c;
  __sincosf(ghalf, &s, &c);
  constexpr unsigned MHI = (M >> 6) & 63u;
  constexpr unsigned MLO = M & 63u;
  constexpr unsigned RHI = (R >> 6) & 63u;
  constexpr unsigned RLO = R & 63u;
  float sL = (__popc((int)(RLO & (unsigned)lane)) & 1) ? -1.f : 1.f;
  float ar, aiS, brS, b0i;
  if constexpr (REAL) {
    ar = c; aiS = 0.f; brS = -s * sL; b0i = 0.f;
  } else {
    float sf, cf;
    __sincosf(phihalf, &sf, &cf);
    ar = c * cf; aiS = (-c * sf) * sL; brS = (-s * cf) * sL; b0i = s * sf;
  }
  f2 arr; arr.x = ar; arr.y = ar;
  f2 aip; aip.x = -aiS; aip.y = aiS;
  f2 aim; aim.x = aiS;  aim.y = -aiS;
  f2 brp; brp.x = brS;  brp.y = brS;
  f2 brm; brm.x = -brS; brm.y = -brS;
  f2 bii; bii.x = -b0i; bii.y = b0i;
  if constexpr (MLO == 0u) {
    constexpr unsigned TB = MHI & (~MHI + 1u);
    #pragma unroll
    for (int r = 0; r < NREG; ++r) {
      if ((r & (int)TB) == 0) {
        int r2 = r ^ (int)MHI;
        const bool rp = ((__builtin_popcount((unsigned)r & RHI)) & 1) != 0;
        f2 a = st[r], b = st[r2];
        st[r]  = rp ? updv<REAL>(a, b, arr, aim, brm, bii) : updv<REAL>(a, b, arr, aip, brp, bii);
        st[r2] = rp ? updv<REAL>(b, a, arr, aip, brp, bii) : updv<REAL>(b, a, arr, aim, brm, bii);
      }
    }
  } else {
    #pragma unroll
    for (int r = 0; r < NREG; ++r) {
      f2 p;
      p.x = shx<MLO>(st[r].x, lane4);
      p.y = shx<MLO>(st[r].y, lane4);
      const bool rp = ((__builtin_popcount((unsigned)r & RHI)) & 1) != 0;
      st[r] = rp ? updv<REAL>(st[r], p, arr, aim, brm, bii) : updv<REAL>(st[r], p, arr, aip, brp, bii);
    }
  }
}

// ---- layer 0 on sparse |0..0> (identity labeling; all masks single-bit) ----
template<int Q>
__device__ __forceinline__ void l0_lane(f2* st, const float* ang, const float* __restrict__ qp, int lane, int lane4) {
  if constexpr (Q < NQ) {
    constexpr unsigned M = PLAN.l0m[Q];
    if constexpr (M < 64u) {
      gate<M, PLAN.l0r[Q], 1, false>(st, 0.5f * (ang[Q] + qp[Q * 2 + 0]), 0.5f * qp[Q * 2 + 1], lane, lane4);
    }
    l0_lane<Q + 1>(st, ang, qp, lane, lane4);
  }
}
template<int Q, unsigned DONE>
__device__ __forceinline__ void l0_reg(f2* st, const float* ang, const float* __restrict__ qp) {
  if constexpr (Q < NQ) {
    constexpr unsigned M = PLAN.l0m[Q];
    if constexpr (M >= 64u) {
      constexpr unsigned TB = (M >> 6) & 63u;
      float sh = 0.5f * (ang[Q] + qp[Q * 2 + 0]);
      float ph = 0.5f * qp[Q * 2 + 1];
      float s, c, sf, cf;
      __sincosf(sh, &s, &c);
      __sincosf(ph, &sf, &cf);
      f2 u0r; u0r.x = c * cf;  u0r.y = c * cf;
      f2 u0i; u0i.x = c * sf;  u0i.y = -c * sf;
      f2 u1r; u1r.x = s * cf;  u1r.y = s * cf;
      f2 u1i; u1i.x = -s * sf; u1i.y = s * sf;
      #pragma unroll
      for (int r = 0; r < 64; ++r) {
        if ((r & ~(int)DONE & 63) == 0) {
          f2 a = st[r];
          int r2 = r | (int)TB;
          st[r]  = cmulv(a, u0r, u0i);
          st[r2] = cmulv(a, u1r, u1i);
        }
      }
      l0_reg<Q + 1, DONE | TB>(st, ang, qp);
    } else {
      l0_reg<Q + 1, DONE>(st, ang, qp);
    }
  }
}

// ---- LDS remap, buffer shared between the block's 2 waves (turn-based) ----
// PAD(a)=a+(a>>5): skewed indexing, injective on [0,2048), write/read identical.
__device__ __forceinline__ int pad(int a) { return a + (a >> 5); }

template<int PH>
__device__ __forceinline__ void remap_body(f2* st, f2* lds, int lane) {
  constexpr int b = PLAN.cb[PH];
  constexpr unsigned LM6 = (1u << b) - 1u;
  constexpr unsigned LM = (1u << (6 + b)) - 1u;
  unsigned B = 0;
  #pragma unroll
  for (int j = 0; j < 6; ++j) B ^= (unsigned)(-(int)((lane >> j) & 1)) & PLAN.phi[PH][j];
  unsigned rBe = (B & LM) | ((B >> 1) & (0x7FFu & ~LM));
  #pragma unroll
  for (int s = 0; s < 2; ++s) {
    #pragma unroll
    for (int r = 0; r < 64; ++r) {
      if (((r >> b) & 1) == s) {
        const int cr = (r & (int)LM6) | ((r >> 1) & (31 & ~(int)LM6));
        lds[pad((cr << 6) | lane)] = st[r];
      }
    }
    asm volatile("s_waitcnt lgkmcnt(0)" ::: "memory");
    #pragma unroll
    for (int rp = 0; rp < 64; ++rp) {
      if (((rp >> b) & 1) == s) {
        st[rp] = lds[pad((int)(rBe ^ PLAN.coffE[PH][rp]))];
      }
    }
    asm volatile("s_waitcnt lgkmcnt(0)" ::: "memory");
  }
}

// turn-based wrapper: barriers at uniform scope; w is wave-uniform; the guarded body
// contains no barriers (only s_waitcnt), so this is barrier-legal.
template<int PH>
__device__ __forceinline__ void remap_shared(f2* st, f2* lds, int lane, int w) {
  #pragma unroll
  for (int turn = 0; turn < 2; ++turn) {
    __syncthreads();
    if (w == turn) remap_body<PH>(st, lds, lane);
  }
}

template<int PH, int I>
__device__ __forceinline__ void do_phase(f2* st, const float* ang, const float* __restrict__ qp, int lane, int lane4) {
  if constexpr (I < 6) {
    constexpr int L = 1 + PH / 2;
    constexpr bool REAL = (L == NL - 1);
    constexpr int q = (PH % 2) * 6 + I;
    constexpr unsigned M = PLAN.gm[PH][I];
    constexpr unsigned R = PLAN.gr[PH][I];
    float th0 = qp[(L * NQ + q) * 2 + 0];
    float ph1 = REAL ? 0.f : 0.5f * qp[(L * NQ + q) * 2 + 1];
    gate<M, R, 64, REAL>(st, 0.5f * (ang[q] + th0), ph1, lane, lane4);
    do_phase<PH, I + 1>(st, ang, qp, lane, lane4);
  }
}

__device__ __forceinline__ float redsum(float v, int lane4) {
  v += shx<1>(v, lane4);
  v += shx<2>(v, lane4);
  v += shx<4>(v, lane4);
  v += shx<8>(v, lane4);
  v += shx<16>(v, lane4);
  v += shx<32>(v, lane4);
  return v;
}
__device__ __forceinline__ float fast_tanh(float x) {
  float e = __expf(2.f * x);
  float r = __builtin_amdgcn_rcpf(e + 1.f);
  return 1.f - 2.f * r;
}

template<int Q>
__device__ __forceinline__ void finish(const f2* acc6, float& outv, int lane, int lane4) {
  if constexpr (Q < NQ) {
    constexpr unsigned RLO = PLAN.rf[Q] & 63u;
    float a = (Q & 1) ? acc6[Q / 2].y : acc6[Q / 2].x;
    float sLn = (__popc((int)(RLO & (unsigned)lane)) & 1) ? -a : a;
    float t = redsum(sLn, lane4);
    if (lane == Q) outv = t;
    finish<Q + 1>(acc6, outv, lane, lane4);
  }
}

// 2 batch elements per block (one per wave), sharing the 16.5KB staging buffer in turns.
// Doubles waves/CU (LDS was the occupancy binder at 1 elem/16.5KB) to hide DS stalls.
__global__ __launch_bounds__(128) void qtr_kernel(const float* __restrict__ x,
                                                  const float* __restrict__ W,
                                                  const float* __restrict__ qp,
                                                  float* __restrict__ out) {
  __shared__ f2 ldsb[2112];  // 16.5KB (2048 + 64 pad slots)
  int tid = threadIdx.x;
  int w = tid >> 6;
  int lane = tid & 63;
  int lane4 = lane << 2;
  int b = blockIdx.x * 2 + w;

  // angles[q] = pi * tanh(dot(x[b], W[q]))
  float xv = x[b * FEAT + lane];
  float ang[NQ];
  #pragma unroll
  for (int q = 0; q < NQ; ++q) {
    float prod = redsum(xv * W[q * FEAT + lane], lane4);
    ang[q] = PI_F * fast_tanh(prod);
  }

  // sparse |0..0>
  f2 st[64];
  st[0].x = (lane == 0) ? 1.f : 0.f;
  st[0].y = 0.f;

  l0_lane<0>(st, ang, qp, lane, lane4);
  l0_reg<0, 0u>(st, ang, qp);

  remap_shared<0>(st, ldsb, lane, w);
  do_phase<0, 0>(st, ang, qp, lane, lane4);
  remap_shared<1>(st, ldsb, lane, w);
  do_phase<1, 0>(st, ang, qp, lane, lane4);
  remap_shared<2>(st, ldsb, lane, w);
  do_phase<2, 0>(st, ang, qp, lane, lane4);
  remap_shared<3>(st, ldsb, lane, w);
  do_phase<3, 0>(st, ang, qp, lane, lane4);

  // probabilities -> 6 packed parity-signed accumulators
  f2 acc6[6];
  #pragma unroll
  for (int j = 0; j < 6; ++j) { acc6[j].x = 0.f; acc6[j].y = 0.f; }
  #pragma unroll
  for (int r = 0; r < 64; ++r) {
    f2 q2 = st[r] * st[r];
    float p = q2.x + q2.y;
    f2 pp; pp.x = p; pp.y = p;
    #pragma unroll
    for (int j = 0; j < 6; ++j) {
      const bool n0 = ((__builtin_popcount(((PLAN.rf[2 * j]     >> 6) & 63u) & (unsigned)r)) & 1) != 0;
      const bool n1 = ((__builtin_popcount(((PLAN.rf[2 * j + 1] >> 6) & 63u) & (unsigned)r)) & 1) != 0;
      f2 sg; sg.x = n0 ? -1.f : 1.f; sg.y = n1 ? -1.f : 1.f;
      acc6[j] = pp * sg + acc6[j];
    }
  }

  float outv = 0.f;
  finish<0>(acc6, outv, lane, lane4);

  if (lane < NQ) out[b * NQ + lane] = outv;
}

}  // namespace

extern "C" void kernel_launch(void* const* d_in, const int* in_sizes, int n_in,
                              void* d_out, int out_size, void* d_ws, size_t ws_size,
                              hipStream_t stream) {
  const float* x  = (const float*)d_in[0];
  const float* W  = (const float*)d_in[1];
  const float* qp = (const float*)d_in[2];
  float* out = (float*)d_out;
  qtr_kernel<<<4096, 128, 0, stream>>>(x, W, qp, out);
}

// Round 17
// 131.685 us; speedup vs baseline: 1.0762x; 1.0762x over previous
//
#include <hip/hip_runtime.h>

namespace {

constexpr int NQ = 12;
constexpr int NL = 3;
constexpr int FEAT = 64;
constexpr float PI_F = 3.14159265358979323846f;

typedef float f2 __attribute__((ext_vector_type(2)));

// ============================ constexpr GF(2) toolkit ============================
constexpr int par12(unsigned x) { int p = 0; for (int i = 0; i < 12; ++i) p ^= (int)((x >> i) & 1u); return p; }
constexpr int lead12(unsigned x) { for (int k = 11; k >= 0; --k) if ((x >> k) & 1u) return k; return -1; }

struct Ech { unsigned v[16] = {}; int n = 0; };
constexpr unsigned ech_reduce(const Ech& E, unsigned x) {
  for (int i = 0; i < E.n; ++i) { int lb = lead12(E.v[i]); if (lb >= 0 && ((x >> lb) & 1u)) x ^= E.v[i]; }
  return x;
}
constexpr bool ech_add(Ech& E, unsigned x) {
  unsigned r = ech_reduce(E, x);
  if (!r) return false;
  int lb = lead12(r);
  int pos = E.n;
  for (int i = 0; i < E.n; ++i) { if (lead12(E.v[i]) < lb) { pos = i; break; } }
  for (int i = E.n; i > pos; --i) E.v[i] = E.v[i - 1];
  E.v[pos] = r; E.n++;
  return true;
}

constexpr unsigned apmat(const unsigned* rows, unsigned v) {
  unsigned o = 0; for (int k = 0; k < 12; ++k) if (par12(rows[k] & v)) o |= 1u << k; return o;
}
constexpr bool inv12(const unsigned* in, unsigned* out) {
  unsigned a[12] = {}, b[12] = {};
  for (int k = 0; k < 12; ++k) { a[k] = in[k]; b[k] = 1u << k; }
  for (int c = 0; c < 12; ++c) {
    int p = -1;
    for (int r = c; r < 12; ++r) if ((a[r] >> c) & 1u) { p = r; break; }
    if (p < 0) return false;
    unsigned t = a[c]; a[c] = a[p]; a[p] = t; t = b[c]; b[c] = b[p]; b[p] = t;
    for (int r = 0; r < 12; ++r) if (r != c && ((a[r] >> c) & 1u)) { a[r] ^= a[c]; b[r] ^= b[c]; }
  }
  for (int k = 0; k < 12; ++k) out[k] = b[k];
  return true;
}
constexpr unsigned dropb(unsigned x, int t) {  // remove bit t, shift higher bits down (11-bit result)
  unsigned lm = (1u << t) - 1u;
  return (x & lm) | ((x >> 1) & (0x7FFu & ~lm));
}

// ============ logical circuit tracking (deferred CNOT ring, verified r1-r16) ============
struct Logical {
  unsigned m[NL][NQ] = {}, rv[NL][NQ] = {}, rf[NQ] = {};
  bool ok = false;
};
constexpr Logical compute_raw() {
  Logical mp{};
  unsigned col[NQ] = {}, row[NQ] = {};
  for (int b = 0; b < NQ; ++b) { col[b] = 1u << b; row[b] = 1u << b; }
  mp.ok = true;
  for (int L = 0; L < NL; ++L) {
    for (int q = 0; q < NQ; ++q) {
      mp.m[L][q]  = col[NQ - 1 - q];
      mp.rv[L][q] = row[NQ - 1 - q];
      if (par12(mp.m[L][q] & mp.rv[L][q]) != 1) mp.ok = false;
    }
    for (int q = 0; q < NQ; ++q) {
      int bc = NQ - 1 - q;
      int bt = NQ - 1 - ((q + 1) % NQ);
      col[bc] ^= col[bt];
      row[bt] ^= row[bc];
    }
  }
  for (int q = 0; q < NQ; ++q) mp.rf[q] = row[NQ - 1 - q];
  return mp;
}

// ============================ phase/remap plan (VERIFIED r10-r16) ============================
struct Plan {
  unsigned l0m[NQ] = {}, l0r[NQ] = {};
  unsigned gm[4][6] = {};
  unsigned gr[4][6] = {};
  unsigned rf[NQ] = {};
  unsigned phi[4][6] = {};
  unsigned coffE[4][64] = {};
  int cb[4] = {};
  bool ok = false;
};

constexpr bool findH(const Ech& G, unsigned rho, unsigned& out) {
  for (unsigned t = 0; t < 12; ++t) {
    unsigned v = 1u << t;
    if (par12(v & rho) == 0 && ech_reduce(G, v)) { out = v; return true; }
  }
  for (unsigned v = 1; v < 4096u; ++v) {
    if (par12(v & rho) == 0 && ech_reduce(G, v)) { out = v; return true; }
  }
  return false;
}

constexpr Plan build_plan() {
  Logical raw = compute_raw();
  Plan P{};
  P.ok = raw.ok;
  for (int q = 0; q < NQ; ++q) { P.l0m[q] = raw.m[0][q]; P.l0r[q] = raw.rv[0][q]; }
  unsigned fwd[12] = {}, invc[12] = {};
  for (int k = 0; k < 12; ++k) { fwd[k] = 1u << k; invc[k] = 1u << k; }
  for (int ph = 0; ph < 4; ++ph) {
    const int L = 1 + ph / 2, q0 = (ph % 2) * 6;
    unsigned ml[6] = {};
    for (int i = 0; i < 6; ++i) ml[i] = raw.m[L][q0 + i];
    bool done = false;
    for (int cbi = 5; cbi >= 0 && !done; --cbi) {
      unsigned rho = fwd[6 + cbi];
      bool bad = false;
      int idx = -1;
      for (int i = 0; i < 6; ++i) if (par12(ml[i] & rho)) { idx = i; break; }
      unsigned uc = 0;
      Ech W{};
      if (idx >= 0) {
        uc = ml[idx];
        for (int i = 0; i < 6; ++i) {
          if (i == idx) continue;
          unsigned w = par12(ml[i] & rho) ? (ml[i] ^ uc) : ml[i];
          ech_add(W, w);
        }
        if (W.n > 5) bad = true;
      } else {
        for (int i = 0; i < 6; ++i) ech_add(W, ml[i]);
        if (W.n > 5) bad = true;
        if (!bad) {
          bool got = false;
          for (unsigned t = 0; t < 12 && !got; ++t) {
            unsigned v = 1u << t;
            if (par12(v & rho)) { uc = v; got = true; }
          }
          if (!got) bad = true;
        }
      }
      if (bad) continue;
      Ech G{};
      for (int i = 0; i < W.n && !bad; ++i) if (!ech_add(G, W.v[i])) bad = true;
      if (!bad && !ech_add(G, uc)) bad = true;
      if (bad) continue;
      unsigned regH[5] = {};
      int nH = W.n;
      for (int i = 0; i < nH; ++i) regH[i] = W.v[i];
      for (int slot = nH; slot < 5 && !bad; ++slot) {
        unsigned v = 0;
        if (!findH(G, rho, v)) { bad = true; break; }
        regH[slot] = v; ech_add(G, v);
      }
      if (bad) continue;
      unsigned lam[6] = {};
      for (int j = 0; j < 6 && !bad; ++j) {
        unsigned cand = invc[j];
        if (par12(cand & rho) != 0 || !ech_reduce(G, cand)) {
          if (!findH(G, rho, cand)) { bad = true; break; }
        }
        lam[j] = cand; ech_add(G, cand);
      }
      if (bad) continue;
      unsigned ncols[12] = {};
      for (int j = 0; j < 6; ++j) ncols[j] = lam[j];
      {
        int w = 0;
        for (int k = 0; k < 6; ++k) ncols[6 + k] = (k == cbi) ? uc : regH[w++];
      }
      unsigned Mrows[12] = {};
      for (int k = 0; k < 12; ++k) {
        unsigned r = 0;
        for (int j = 0; j < 12; ++j) r |= ((ncols[j] >> k) & 1u) << j;
        Mrows[k] = r;
      }
      unsigned fnew[12] = {};
      if (!inv12(Mrows, fnew)) continue;
      bool okp = true;
      unsigned gmv[6] = {}, grv[6] = {};
      for (int i = 0; i < 6 && okp; ++i) {
        unsigned SM = apmat(fnew, ml[i]);
        if (SM & 63u) okp = false;
        unsigned sg = 0;
        for (int k = 0; k < 12; ++k) if (par12(raw.rv[L][q0 + i] & ncols[k])) sg |= 1u << k;
        if (par12(SM & sg) != 1) okp = false;
        gmv[i] = SM; grv[i] = sg;
      }
      unsigned phj[6] = {}, Ust[6] = {};
      for (int j = 0; j < 6 && okp; ++j) {
        phj[j] = apmat(fwd, lam[j]);
        if ((phj[j] >> (6 + cbi)) & 1u) okp = false;
      }
      for (int k = 0; k < 6 && okp; ++k) {
        Ust[k] = apmat(fwd, ncols[6 + k]);
        if (((Ust[k] >> (6 + cbi)) & 1u) != (unsigned)(k == cbi ? 1 : 0)) okp = false;
      }
      if (!okp) continue;
      P.cb[ph] = cbi;
      for (int j = 0; j < 6; ++j) P.phi[ph][j] = phj[j];
      for (int rp = 0; rp < 64; ++rp) {
        unsigned psi = 0;
        for (int i = 0; i < 6; ++i) if ((rp >> i) & 1) psi ^= Ust[i];
        P.coffE[ph][rp] = dropb(psi, 6 + cbi);
      }
      for (int i = 0; i < 6; ++i) { P.gm[ph][i] = gmv[i]; P.gr[ph][i] = grv[i]; }
      for (int k = 0; k < 12; ++k) { fwd[k] = fnew[k]; invc[k] = ncols[k]; }
      done = true;
    }
    if (!done) { P.ok = false; return P; }
  }
  for (int q = 0; q < NQ; ++q) {
    unsigned sg = 0;
    for (int k = 0; k < 12; ++k) if (par12(raw.rf[q] & invc[k])) sg |= 1u << k;
    P.rf[q] = sg;
  }
  return P;
}

constexpr Plan PLAN = build_plan();
static_assert(PLAN.ok, "plan construction failed");

// ============================ math (plain C++, verified r14 = fastest) ============================
// CDNA4 has no packed-FP32 rate doubling (157.3 TF peak == scalar FMA rate), so scalar
// compiler-generated FMAs reading AGPR-resident state directly ARE the arithmetic floor.
__device__ __forceinline__ f2 shuf(f2 a) { return __builtin_shufflevector(a, a, 1, 0); }

template<bool REAL>
__device__ __forceinline__ f2 updv(f2 a, f2 p, f2 arr, f2 aii, f2 brr, f2 bii) {
  f2 t = a * arr;
  if constexpr (!REAL) t = shuf(a) * aii + t;
  t = p * brr + t;
  if constexpr (!REAL) t = shuf(p) * bii + t;
  return t;
}
__device__ __forceinline__ f2 cmulv(f2 a, f2 urr, f2 uri) {
  return shuf(a) * uri + a * urr;
}

template<unsigned MLO>
__device__ __forceinline__ float shx(float v, int lane4) {
  if constexpr (MLO == 0u) {
    return v;
  } else if constexpr (MLO < 32u) {
    constexpr int off = (int)((MLO << 10) | 0x1fu);
    return __int_as_float(__builtin_amdgcn_ds_swizzle(__float_as_int(v), off));
  } else {
    int addr = lane4 ^ (int)(MLO << 2);
    return __int_as_float(__builtin_amdgcn_ds_bpermute(addr, __float_as_int(v)));
  }
}

template<unsigned M, unsigned R, int NREG, bool REAL>
__device__ __forceinline__ void gate(f2* st, float ghalf, float phihalf, int lane, int lane4) {
  float s, c;
  __sincosf(ghalf, &s, &c);
  constexpr unsigned MHI = (M >> 6) & 63u;
  constexpr unsigned MLO = M & 63u;
  constexpr unsigned RHI = (R >> 6) & 63u;
  constexpr unsigned RLO = R & 63u;
  float sL = (__popc((int)(RLO & (unsigned)lane)) & 1) ? -1.f : 1.f;
  float ar, aiS, brS, b0i;
  if constexpr (REAL) {
    ar = c; aiS = 0.f; brS = -s * sL; b0i = 0.f;
  } else {
    float sf, cf;
    __sincosf(phihalf, &sf, &cf);
    ar = c * cf; aiS = (-c * sf) * sL; brS = (-s * cf) * sL; b0i = s * sf;
  }
  f2 arr; arr.x = ar; arr.y = ar;
  f2 aip; aip.x = -aiS; aip.y = aiS;
  f2 aim; aim.x = aiS;  aim.y = -aiS;
  f2 brp; brp.x = brS;  brp.y = brS;
  f2 brm; brm.x = -brS; brm.y = -brS;
  f2 bii; bii.x = -b0i; bii.y = b0i;
  if constexpr (MLO == 0u) {
    constexpr unsigned TB = MHI & (~MHI + 1u);
    #pragma unroll
    for (int r = 0; r < NREG; ++r) {
      if ((r & (int)TB) == 0) {
        int r2 = r ^ (int)MHI;
        const bool rp = ((__builtin_popcount((unsigned)r & RHI)) & 1) != 0;
        f2 a = st[r], b = st[r2];
        st[r]  = rp ? updv<REAL>(a, b, arr, aim, brm, bii) : updv<REAL>(a, b, arr, aip, brp, bii);
        st[r2] = rp ? updv<REAL>(b, a, arr, aip, brp, bii) : updv<REAL>(b, a, arr, aim, brm, bii);
      }
    }
  } else {
    #pragma unroll
    for (int r = 0; r < NREG; ++r) {
      f2 p;
      p.x = shx<MLO>(st[r].x, lane4);
      p.y = shx<MLO>(st[r].y, lane4);
      const bool rp = ((__builtin_popcount((unsigned)r & RHI)) & 1) != 0;
      st[r] = rp ? updv<REAL>(st[r], p, arr, aim, brm, bii) : updv<REAL>(st[r], p, arr, aip, brp, bii);
    }
  }
}

// ---- layer 0 on sparse |0..0> (identity labeling; all masks single-bit) ----
template<int Q>
__device__ __forceinline__ void l0_lane(f2* st, const float* ang, const float* __restrict__ qp, int lane, int lane4) {
  if constexpr (Q < NQ) {
    constexpr unsigned M = PLAN.l0m[Q];
    if constexpr (M < 64u) {
      gate<M, PLAN.l0r[Q], 1, false>(st, 0.5f * (ang[Q] + qp[Q * 2 + 0]), 0.5f * qp[Q * 2 + 1], lane, lane4);
    }
    l0_lane<Q + 1>(st, ang, qp, lane, lane4);
  }
}
template<int Q, unsigned DONE>
__device__ __forceinline__ void l0_reg(f2* st, const float* ang, const float* __restrict__ qp) {
  if constexpr (Q < NQ) {
    constexpr unsigned M = PLAN.l0m[Q];
    if constexpr (M >= 64u) {
      constexpr unsigned TB = (M >> 6) & 63u;
      float sh = 0.5f * (ang[Q] + qp[Q * 2 + 0]);
      float ph = 0.5f * qp[Q * 2 + 1];
      float s, c, sf, cf;
      __sincosf(sh, &s, &c);
      __sincosf(ph, &sf, &cf);
      f2 u0r; u0r.x = c * cf;  u0r.y = c * cf;
      f2 u0i; u0i.x = c * sf;  u0i.y = -c * sf;
      f2 u1r; u1r.x = s * cf;  u1r.y = s * cf;
      f2 u1i; u1i.x = -s * sf; u1i.y = s * sf;
      #pragma unroll
      for (int r = 0; r < 64; ++r) {
        if ((r & ~(int)DONE & 63) == 0) {
          f2 a = st[r];
          int r2 = r | (int)TB;
          st[r]  = cmulv(a, u0r, u0i);
          st[r2] = cmulv(a, u1r, u1i);
        }
      }
      l0_reg<Q + 1, DONE | TB>(st, ang, qp);
    } else {
      l0_reg<Q + 1, DONE>(st, ang, qp);
    }
  }
}

// ---- LDS remap: relabel storage (2 stages x 16KB, wave-local, no barriers) ----
// sc(a) = a ^ ((a>>4)&15) ^ ((a>>8)&7): XOR bit-fold, bijective on [0,2048) (bits >=4
// unchanged -> decode low bits). Applied identically to writes and reads (same LDS-slot
// permutation -> correctness invariant). Folds ALL high address bits into the 4 bank-slot
// bits, fixing the read-set rank deficiency that the additive +(a>>5) skew only halved
// (17.8M -> 8.2M conflicts, r6 vs r10). Write side stays conflict-free: per instruction,
// low4' covers each slot exactly 2x per 32 lanes (the b64 minimum).
__device__ __forceinline__ int sc(int a) { return a ^ ((a >> 4) & 15) ^ ((a >> 8) & 7); }

template<int PH>
__device__ __forceinline__ void remap(f2* st, f2* lds, int lane) {
  constexpr int b = PLAN.cb[PH];
  constexpr unsigned LM6 = (1u << b) - 1u;
  constexpr unsigned LM = (1u << (6 + b)) - 1u;
  unsigned B = 0;
  #pragma unroll
  for (int j = 0; j < 6; ++j) B ^= (unsigned)(-(int)((lane >> j) & 1)) & PLAN.phi[PH][j];
  unsigned rBe = (B & LM) | ((B >> 1) & (0x7FFu & ~LM));
  #pragma unroll
  for (int s = 0; s < 2; ++s) {
    #pragma unroll
    for (int r = 0; r < 64; ++r) {
      if (((r >> b) & 1) == s) {
        const int cr = (r & (int)LM6) | ((r >> 1) & (31 & ~(int)LM6));
        lds[sc((cr << 6) | lane)] = st[r];
      }
    }
    asm volatile("s_waitcnt lgkmcnt(0)" ::: "memory");
    #pragma unroll
    for (int rp = 0; rp < 64; ++rp) {
      if (((rp >> b) & 1) == s) {
        st[rp] = lds[sc((int)(rBe ^ PLAN.coffE[PH][rp]))];
      }
    }
    asm volatile("s_waitcnt lgkmcnt(0)" ::: "memory");
  }
}

template<int PH, int I>
__device__ __forceinline__ void do_phase(f2* st, const float* ang, const float* __restrict__ qp, int lane, int lane4) {
  if constexpr (I < 6) {
    constexpr int L = 1 + PH / 2;
    constexpr bool REAL = (L == NL - 1);
    constexpr int q = (PH % 2) * 6 + I;
    constexpr unsigned M = PLAN.gm[PH][I];
    constexpr unsigned R = PLAN.gr[PH][I];
    float th0 = qp[(L * NQ + q) * 2 + 0];
    float ph1 = REAL ? 0.f : 0.5f * qp[(L * NQ + q) * 2 + 1];
    gate<M, R, 64, REAL>(st, 0.5f * (ang[q] + th0), ph1, lane, lane4);
    do_phase<PH, I + 1>(st, ang, qp, lane, lane4);
  }
}

__device__ __forceinline__ float redsum(float v, int lane4) {
  v += shx<1>(v, lane4);
  v += shx<2>(v, lane4);
  v += shx<4>(v, lane4);
  v += shx<8>(v, lane4);
  v += shx<16>(v, lane4);
  v += shx<32>(v, lane4);
  return v;
}
__device__ __forceinline__ float fast_tanh(float x) {
  float e = __expf(2.f * x);
  float r = __builtin_amdgcn_rcpf(e + 1.f);
  return 1.f - 2.f * r;
}

template<int Q>
__device__ __forceinline__ void finish(const f2* acc6, float& outv, int lane, int lane4) {
  if constexpr (Q < NQ) {
    constexpr unsigned RLO = PLAN.rf[Q] & 63u;
    float a = (Q & 1) ? acc6[Q / 2].y : acc6[Q / 2].x;
    float sLn = (__popc((int)(RLO & (unsigned)lane)) & 1) ? -a : a;
    float t = redsum(sLn, lane4);
    if (lane == Q) outv = t;
    finish<Q + 1>(acc6, outv, lane, lane4);
  }
}

__global__ __launch_bounds__(64, 2) void qtr_kernel(const float* __restrict__ x,
                                                    const float* __restrict__ W,
                                                    const float* __restrict__ qp,
                                                    float* __restrict__ out) {
  __shared__ f2 ldsb[2048];  // exactly 16KB -> 10 blocks/CU (was 16.5KB -> 9)
  int b = blockIdx.x;
  int lane = threadIdx.x;
  int lane4 = lane << 2;

  // angles[q] = pi * tanh(dot(x[b], W[q]))
  float xv = x[b * FEAT + lane];
  float ang[NQ];
  #pragma unroll
  for (int q = 0; q < NQ; ++q) {
    float prod = redsum(xv * W[q * FEAT + lane], lane4);
    ang[q] = PI_F * fast_tanh(prod);
  }

  // sparse |0..0>
  f2 st[64];
  st[0].x = (lane == 0) ? 1.f : 0.f;
  st[0].y = 0.f;

  l0_lane<0>(st, ang, qp, lane, lane4);
  l0_reg<0, 0u>(st, ang, qp);

  remap<0>(st, ldsb, lane);
  do_phase<0, 0>(st, ang, qp, lane, lane4);
  remap<1>(st, ldsb, lane);
  do_phase<1, 0>(st, ang, qp, lane, lane4);
  remap<2>(st, ldsb, lane);
  do_phase<2, 0>(st, ang, qp, lane, lane4);
  remap<3>(st, ldsb, lane);
  do_phase<3, 0>(st, ang, qp, lane, lane4);

  // probabilities -> 6 packed parity-signed accumulators
  f2 acc6[6];
  #pragma unroll
  for (int j = 0; j < 6; ++j) { acc6[j].x = 0.f; acc6[j].y = 0.f; }
  #pragma unroll
  for (int r = 0; r < 64; ++r) {
    f2 q2 = st[r] * st[r];
    float p = q2.x + q2.y;
    f2 pp; pp.x = p; pp.y = p;
    #pragma unroll
    for (int j = 0; j < 6; ++j) {
      const bool n0 = ((__builtin_popcount(((PLAN.rf[2 * j]     >> 6) & 63u) & (unsigned)r)) & 1) != 0;
      const bool n1 = ((__builtin_popcount(((PLAN.rf[2 * j + 1] >> 6) & 63u) & (unsigned)r)) & 1) != 0;
      f2 sg; sg.x = n0 ? -1.f : 1.f; sg.y = n1 ? -1.f : 1.f;
      acc6[j] = pp * sg + acc6[j];
    }
  }

  float outv = 0.f;
  finish<0>(acc6, outv, lane, lane4);

  if (lane < NQ) out[b * NQ + lane] = outv;
}

}  // namespace

extern "C" void kernel_launch(void* const* d_in, const int* in_sizes, int n_in,
                              void* d_out, int out_size, void* d_ws, size_t ws_size,
                              hipStream_t stream) {
  const float* x  = (const float*)d_in[0];
  const float* W  = (const float*)d_in[1];
  const float* qp = (const float*)d_in[2];
  float* out = (float*)d_out;
  qtr_kernel<<<8192, 64, 0, stream>>>(x, W, qp, out);
}